// Round 1
// baseline (108.690 us; speedup 1.0000x reference)
//
#include <hip/hip_runtime.h>

#define SEQ   2048
#define EMB   128
#define NH    16
#define DKW   8
#define NB    2
#define QBLK  128           // query rows per block (1 thread per row)
#define NQT   (SEQ / QBLK)  // 16
#define NBH   (NB * NH)     // 32

// Kernel 1: per (b, h, q-tile). Stage K = cos(x+theta) for the whole head in
// LDS (64 KiB), then each thread does a full-softmax row (no max needed:
// |score| <= sqrt(8)) and writes attn-output [B,S,E] layout into ws.
__global__ __launch_bounds__(QBLK) void qattn_kernel(const float* __restrict__ x,
                                                     const float* __restrict__ theta,
                                                     float* __restrict__ ws) {
    __shared__ float4 K4[SEQ * 2];  // K4[2t], K4[2t+1] = 8 floats of token t

    const int tid = threadIdx.x;
    const int bid = blockIdx.x;
    const int bh  = bid % NBH;   // (b,h)
    const int qt  = bid / NBH;   // q tile
    const int b   = bh >> 4;
    const int h   = bh & 15;

    float th[DKW];
#pragma unroll
    for (int d = 0; d < DKW; ++d) th[d] = theta[d];

    // token t, head h occupies float4 slots (t*32 + h*2) and (+1) of x[b]
    const float4* x4 = (const float4*)x + (size_t)b * SEQ * (EMB / 4) + h * 2;

    for (int t = tid; t < SEQ; t += QBLK) {
        float4 lo = x4[(size_t)t * (EMB / 4)];
        float4 hi = x4[(size_t)t * (EMB / 4) + 1];
        float4 klo, khi;
        klo.x = __cosf(lo.x + th[0]);
        klo.y = __cosf(lo.y + th[1]);
        klo.z = __cosf(lo.z + th[2]);
        klo.w = __cosf(lo.w + th[3]);
        khi.x = __cosf(hi.x + th[4]);
        khi.y = __cosf(hi.y + th[5]);
        khi.z = __cosf(hi.z + th[6]);
        khi.w = __cosf(hi.w + th[7]);
        K4[t * 2]     = klo;
        K4[t * 2 + 1] = khi;
    }
    __syncthreads();

    const int qrow = qt * QBLK + tid;
    const float4 qlo = K4[qrow * 2];
    const float4 qhi = K4[qrow * 2 + 1];
    // exp(s/sqrt(8)) = exp2(s * (1/sqrt(8) * log2(e)))
    const float SCALE = 0.35355339059327373f * 1.4426950408889634f;

    float  l  = 0.0f;
    float4 a0 = make_float4(0.f, 0.f, 0.f, 0.f);
    float4 a1 = make_float4(0.f, 0.f, 0.f, 0.f);

#pragma unroll 8
    for (int t = 0; t < SEQ; ++t) {
        float4 klo = K4[t * 2];
        float4 khi = K4[t * 2 + 1];
        float s = qlo.x * klo.x;
        s = fmaf(qlo.y, klo.y, s);
        s = fmaf(qlo.z, klo.z, s);
        s = fmaf(qlo.w, klo.w, s);
        s = fmaf(qhi.x, khi.x, s);
        s = fmaf(qhi.y, khi.y, s);
        s = fmaf(qhi.z, khi.z, s);
        s = fmaf(qhi.w, khi.w, s);
        float p = __builtin_exp2f(s * SCALE);
        l += p;
        a0.x = fmaf(p, klo.x, a0.x);
        a0.y = fmaf(p, klo.y, a0.y);
        a0.z = fmaf(p, klo.z, a0.z);
        a0.w = fmaf(p, klo.w, a0.w);
        a1.x = fmaf(p, khi.x, a1.x);
        a1.y = fmaf(p, khi.y, a1.y);
        a1.z = fmaf(p, khi.z, a1.z);
        a1.w = fmaf(p, khi.w, a1.w);
    }

    float inv = 1.0f / l;
    a0.x *= inv; a0.y *= inv; a0.z *= inv; a0.w *= inv;
    a1.x *= inv; a1.y *= inv; a1.z *= inv; a1.w *= inv;

    float4* o = (float4*)ws + ((size_t)(b * SEQ + qrow)) * (EMB / 4) + h * 2;
    o[0] = a0;
    o[1] = a1;
}

// Kernel 2: out[r][e] = sum_k ws[r][k] * W[e][k]   (r = 0..4095, e,k = 0..127)
// W staged transposed in LDS with stride 132 (pad 4) so compute-side
// ds_read_b128 across lanes is conflict-free.
#define K2_ROWS 16
#define K2_THREADS 512
#define WT_STRIDE 132

__global__ __launch_bounds__(K2_THREADS) void combine_kernel(const float* __restrict__ ws,
                                                             const float* __restrict__ W,
                                                             float* __restrict__ out) {
    __shared__ float Wt[128 * WT_STRIDE];   // Wt[k*132 + e] = W[e][k]
    __shared__ float Xs[K2_ROWS * 128];

    const int tid   = threadIdx.x;
    const int rbase = blockIdx.x * K2_ROWS;

    for (int i = tid; i < 128 * 128; i += K2_THREADS) {
        int e = i >> 7, k = i & 127;        // coalesced global read
        Wt[k * WT_STRIDE + e] = W[i];       // 8-way LDS write conflict, one-time
    }
    for (int i = tid; i < K2_ROWS * 128; i += K2_THREADS) {
        Xs[i] = ws[(size_t)rbase * 128 + i];
    }
    __syncthreads();

    const int r = tid >> 5;   // 0..15 (row within tile)
    const int g = tid & 31;   // column group: outputs e = 4g..4g+3
    float4 acc = make_float4(0.f, 0.f, 0.f, 0.f);

    const float4* X4 = (const float4*)&Xs[r * 128];
#pragma unroll
    for (int kc = 0; kc < 32; ++kc) {
        float4 x4 = X4[kc];  // broadcast within row group
#pragma unroll
        for (int j = 0; j < 4; ++j) {
            int k = kc * 4 + j;
            float4 w = *(const float4*)&Wt[k * WT_STRIDE + g * 4];
            float xv = (j == 0) ? x4.x : (j == 1) ? x4.y : (j == 2) ? x4.z : x4.w;
            acc.x = fmaf(xv, w.x, acc.x);
            acc.y = fmaf(xv, w.y, acc.y);
            acc.z = fmaf(xv, w.z, acc.z);
            acc.w = fmaf(xv, w.w, acc.w);
        }
    }

    ((float4*)out)[(size_t)(rbase + r) * 32 + g] = acc;
}

extern "C" void kernel_launch(void* const* d_in, const int* in_sizes, int n_in,
                              void* d_out, int out_size, void* d_ws, size_t ws_size,
                              hipStream_t stream) {
    const float* x     = (const float*)d_in[0];
    const float* theta = (const float*)d_in[1];
    const float* W     = (const float*)d_in[2];
    float* out = (float*)d_out;
    float* ws  = (float*)d_ws;   // needs B*S*E*4 = 2 MiB

    qattn_kernel<<<NBH * NQT, QBLK, 0, stream>>>(x, theta, ws);
    combine_kernel<<<(NB * SEQ) / K2_ROWS, K2_THREADS, 0, stream>>>(ws, W, out);
}

// Round 2
// 82.171 us; speedup vs baseline: 1.3227x; 1.3227x over previous
//
#include <hip/hip_runtime.h>

#define SEQ   2048
#define EMB   128
#define NH    16
#define DKW   8
#define NB    2
#define QBLK  128            // query rows per block
#define NCHUNK 4             // t-chunks (waves-level split of the key loop)
#define TCHUNK (SEQ / NCHUNK)          // 512
#define K1_THREADS (QBLK * NCHUNK)     // 512
#define NQT   (SEQ / QBLK)   // 16
#define NBH   (NB * NH)      // 32

// Kernel 1: per (b, h, q-tile). Stage K = cos(x+theta) for the whole head in
// LDS (64 KiB). thread = (chunk, row): each of the 4 chunk-groups processes a
// disjoint 512-token slice of the key stream for its query row (softmax needs
// no max: |score| <= sqrt(8)), then partials (l, sum p*k) reduce through LDS.
__global__ __launch_bounds__(K1_THREADS, 4) void qattn_kernel(const float* __restrict__ x,
                                                              const float* __restrict__ theta,
                                                              float* __restrict__ ws) {
    __shared__ float4 K4[SEQ * 2];  // K4[2t], K4[2t+1] = 8 floats of token t

    const int tid = threadIdx.x;
    const int bid = blockIdx.x;
    const int bh  = bid % NBH;   // (b,h)
    const int qt  = bid / NBH;   // q tile
    const int b   = bh >> 4;
    const int h   = bh & 15;

    float th[DKW];
#pragma unroll
    for (int d = 0; d < DKW; ++d) th[d] = theta[d];

    // token t, head h occupies float4 slots (t*32 + h*2) and (+1) of x[b]
    const float4* x4 = (const float4*)x + (size_t)b * SEQ * (EMB / 4) + h * 2;

    for (int t = tid; t < SEQ; t += K1_THREADS) {
        float4 lo = x4[(size_t)t * (EMB / 4)];
        float4 hi = x4[(size_t)t * (EMB / 4) + 1];
        float4 klo, khi;
        klo.x = __cosf(lo.x + th[0]);
        klo.y = __cosf(lo.y + th[1]);
        klo.z = __cosf(lo.z + th[2]);
        klo.w = __cosf(lo.w + th[3]);
        khi.x = __cosf(hi.x + th[4]);
        khi.y = __cosf(hi.y + th[5]);
        khi.z = __cosf(hi.z + th[6]);
        khi.w = __cosf(hi.w + th[7]);
        K4[t * 2]     = klo;
        K4[t * 2 + 1] = khi;
    }
    __syncthreads();

    const int row   = tid & (QBLK - 1);
    const int chunk = tid >> 7;           // 0..3
    const int qrow  = qt * QBLK + row;

    // pre-scale q: exp((q.k)/sqrt(8)) = exp2((q*C).k), C = log2(e)/sqrt(8)
    const float C = 0.35355339059327373f * 1.4426950408889634f;
    float4 qlo = K4[qrow * 2];
    float4 qhi = K4[qrow * 2 + 1];
    qlo.x *= C; qlo.y *= C; qlo.z *= C; qlo.w *= C;
    qhi.x *= C; qhi.y *= C; qhi.z *= C; qhi.w *= C;

    float  l  = 0.0f;
    float4 a0 = make_float4(0.f, 0.f, 0.f, 0.f);
    float4 a1 = make_float4(0.f, 0.f, 0.f, 0.f);

    const float4* Kp = &K4[chunk * TCHUNK * 2];
#pragma unroll 8
    for (int t = 0; t < TCHUNK; ++t) {
        float4 klo = Kp[t * 2];
        float4 khi = Kp[t * 2 + 1];
        float s = qlo.x * klo.x;
        s = fmaf(qlo.y, klo.y, s);
        s = fmaf(qlo.z, klo.z, s);
        s = fmaf(qlo.w, klo.w, s);
        s = fmaf(qhi.x, khi.x, s);
        s = fmaf(qhi.y, khi.y, s);
        s = fmaf(qhi.z, khi.z, s);
        s = fmaf(qhi.w, khi.w, s);
        float p = __builtin_exp2f(s);
        l += p;
        a0.x = fmaf(p, klo.x, a0.x);
        a0.y = fmaf(p, klo.y, a0.y);
        a0.z = fmaf(p, klo.z, a0.z);
        a0.w = fmaf(p, klo.w, a0.w);
        a1.x = fmaf(p, khi.x, a1.x);
        a1.y = fmaf(p, khi.y, a1.y);
        a1.z = fmaf(p, khi.z, a1.z);
        a1.w = fmaf(p, khi.w, a1.w);
    }

    // ---- reduce partials across the 4 chunk-groups (reuse K4 LDS) ----
    __syncthreads();                       // all K4 reads done
    float* red = (float*)K4;               // (NCHUNK-1)*QBLK*9 floats = 13.5 KB
    if (chunk != 0) {
        int base = (tid - QBLK) * 9;       // stride 9: conflict-free (gcd(9,32)=1)
        red[base + 0] = a0.x; red[base + 1] = a0.y;
        red[base + 2] = a0.z; red[base + 3] = a0.w;
        red[base + 4] = a1.x; red[base + 5] = a1.y;
        red[base + 6] = a1.z; red[base + 7] = a1.w;
        red[base + 8] = l;
    }
    __syncthreads();
    if (chunk == 0) {
#pragma unroll
        for (int c = 0; c < NCHUNK - 1; ++c) {
            int base = (c * QBLK + row) * 9;
            a0.x += red[base + 0]; a0.y += red[base + 1];
            a0.z += red[base + 2]; a0.w += red[base + 3];
            a1.x += red[base + 4]; a1.y += red[base + 5];
            a1.z += red[base + 6]; a1.w += red[base + 7];
            l    += red[base + 8];
        }
        float inv = 1.0f / l;
        a0.x *= inv; a0.y *= inv; a0.z *= inv; a0.w *= inv;
        a1.x *= inv; a1.y *= inv; a1.z *= inv; a1.w *= inv;

        float4* o = (float4*)ws + ((size_t)(b * SEQ + qrow)) * (EMB / 4) + h * 2;
        o[0] = a0;
        o[1] = a1;
    }
}

// Kernel 2: out[r][e] = sum_k ws[r][k] * W[e][k]   (r = 0..4095, e,k = 0..127)
#define K2_ROWS 16
#define K2_THREADS 512
#define WT_STRIDE 132

__global__ __launch_bounds__(K2_THREADS) void combine_kernel(const float* __restrict__ ws,
                                                             const float* __restrict__ W,
                                                             float* __restrict__ out) {
    __shared__ float Wt[128 * WT_STRIDE];   // Wt[k*132 + e] = W[e][k]
    __shared__ float Xs[K2_ROWS * 128];

    const int tid   = threadIdx.x;
    const int rbase = blockIdx.x * K2_ROWS;

    for (int i = tid; i < 128 * 128; i += K2_THREADS) {
        int e = i >> 7, k = i & 127;        // coalesced global read
        Wt[k * WT_STRIDE + e] = W[i];
    }
    for (int i = tid; i < K2_ROWS * 128; i += K2_THREADS) {
        Xs[i] = ws[(size_t)rbase * 128 + i];
    }
    __syncthreads();

    const int r = tid >> 5;   // 0..15 (row within tile)
    const int g = tid & 31;   // column group: outputs e = 4g..4g+3
    float4 acc = make_float4(0.f, 0.f, 0.f, 0.f);

    const float4* X4 = (const float4*)&Xs[r * 128];
#pragma unroll
    for (int kc = 0; kc < 32; ++kc) {
        float4 x4 = X4[kc];  // broadcast within row group
#pragma unroll
        for (int j = 0; j < 4; ++j) {
            int k = kc * 4 + j;
            float4 w = *(const float4*)&Wt[k * WT_STRIDE + g * 4];
            float xv = (j == 0) ? x4.x : (j == 1) ? x4.y : (j == 2) ? x4.z : x4.w;
            acc.x = fmaf(xv, w.x, acc.x);
            acc.y = fmaf(xv, w.y, acc.y);
            acc.z = fmaf(xv, w.z, acc.z);
            acc.w = fmaf(xv, w.w, acc.w);
        }
    }

    ((float4*)out)[(size_t)(rbase + r) * 32 + g] = acc;
}

extern "C" void kernel_launch(void* const* d_in, const int* in_sizes, int n_in,
                              void* d_out, int out_size, void* d_ws, size_t ws_size,
                              hipStream_t stream) {
    const float* x     = (const float*)d_in[0];
    const float* theta = (const float*)d_in[1];
    const float* W     = (const float*)d_in[2];
    float* out = (float*)d_out;
    float* ws  = (float*)d_ws;   // needs B*S*E*4 = 2 MiB

    qattn_kernel<<<NBH * NQT, K1_THREADS, 0, stream>>>(x, theta, ws);
    combine_kernel<<<(NB * SEQ) / K2_ROWS, K2_THREADS, 0, stream>>>(ws, W, out);
}